// Round 15
// baseline (709.687 us; speedup 1.0000x reference)
//
#include <hip/hip_runtime.h>
#include <stdint.h>

// Problem constants
static constexpr int H_ = 200, W_ = 200, HW_ = 40000;
static constexpr int C_ = 512;
static constexpr int NANCH = 360000;   // HW_ * 9
static constexpr int KPRE = 1000;
static constexpr int KPOST = 100;
static constexpr int KSEL = 1400;      // approx candidate margin (top-1000 + 400)
static constexpr int PXCAP = 4096;     // candidate pixel cap (est npx ~1600)
static constexpr int KSPLIT = 8;       // exact-gemm K split (4608 = 8 x 576)
static constexpr int FT = 212;         // feat_t padded dim, (y,x) real at +1
static constexpr int FP = 202;         // feat_px padded dim, (y,x) real at +1

typedef __attribute__((ext_vector_type(8))) short bf16x8;
typedef __attribute__((ext_vector_type(4))) float f32x4;

__device__ inline ushort f2bf(float f) {               // RNE float->bf16 bits
    unsigned u = __float_as_uint(f);
    u += 0x7FFFu + ((u >> 16) & 1u);
    return (ushort)(u >> 16);
}
__device__ inline float bf2f(ushort h) { return __uint_as_float(((unsigned)h) << 16); }

// async global->LDS 16B: per-lane global src, LDS dst = wave-uniform base + lane*16
typedef const __attribute__((address_space(1))) uint32_t gas_u32;
typedef __attribute__((address_space(3))) uint32_t las_u32;
__device__ __forceinline__ void gload_lds16(const void* g, void* l) {
    __builtin_amdgcn_global_load_lds((gas_u32*)(uintptr_t)g, (las_u32*)(uintptr_t)l, 16, 0, 0);
}

// ---------------------------------------------------------------------------
__global__ void k_zero_u32(unsigned* __restrict__ p, int n) {
    int i = blockIdx.x * 256 + threadIdx.x;
    if (i < n) p[i] = 0u;
}

// Border-only zeroing (interiors fully overwritten by k_feat_t/k_feat_px).
__global__ void k_zero_border_t(ushort* __restrict__ feat_t) {
    int t = blockIdx.x * 256 + threadIdx.x;
    int total = 4944 * 64;           // 512 bf16 = 64 x uint4 per px
    if (t >= total) return;
    int px = t >> 6, part = t & 63;
    int y, x;
    if (px < 2544) { int ri = px / 212; x = px - ri * 212; y = (ri == 0) ? 0 : 200 + ri; }
    else { int q = px - 2544; int r12 = q / 12; int c = q - r12 * 12; y = 1 + r12; x = (c == 0) ? 0 : 200 + c; }
    uint4 z = {0u, 0u, 0u, 0u};
    *(uint4*)&feat_t[((size_t)y * FT + x) * 512 + part * 8] = z;
}

__global__ void k_zero_border_px(float* __restrict__ feat_px) {
    int t = blockIdx.x * 256 + threadIdx.x;
    int total = 804 * 128;           // 512 f32 = 128 x float4 per px
    if (t >= total) return;
    int px = t >> 7, part = t & 127;
    int y, x;
    if (px < 202)      { y = 0;   x = px; }
    else if (px < 404) { y = 201; x = px - 202; }
    else if (px < 604) { x = 0;   y = 1 + (px - 404); }
    else               { x = 201; y = 1 + (px - 604); }
    float4 z = {0.f, 0.f, 0.f, 0.f};
    *(float4*)&feat_px[((size_t)y * FP + x) * 512 + part * 4] = z;
}

// ---------------------------------------------------------------------------
// feat [512][200][200] f32 -> feat_t [212][212][512] bf16 (zero-padded)
// ---------------------------------------------------------------------------
__global__ void k_feat_t(const float* __restrict__ feat, ushort* __restrict__ feat_t) {
    __shared__ ushort lt[32 * 8 * 33];
    int x0 = blockIdx.x * 32, y0 = blockIdx.y * 8, ci0 = blockIdx.z * 32;
    int tid = threadIdx.x;
    for (int u = tid; u < 8192; u += 256) {
        int ciL = u >> 8, rem = u & 255;
        int yy = rem >> 5, xx = rem & 31;
        int x = x0 + xx;
        float v = (x < W_) ? feat[(size_t)(ci0 + ciL) * HW_ + (y0 + yy) * W_ + x] : 0.f;
        lt[(ciL * 8 + yy) * 33 + xx] = f2bf(v);
    }
    __syncthreads();
    for (int u = tid; u < 1024; u += 256) {
        int pxu = u >> 2, part = u & 3;
        int yy = pxu >> 5, xx = pxu & 31;
        if (x0 + xx >= W_) continue;
        ushort tmp[8];
#pragma unroll
        for (int k = 0; k < 8; ++k) tmp[k] = lt[((part * 8 + k) * 8 + yy) * 33 + xx];
        *(uint4*)&feat_t[((size_t)(y0 + yy + 1) * FT + (x0 + xx + 1)) * 512 + ci0 + part * 8] =
            *(const uint4*)&tmp[0];
    }
}

// feat -> feat_px [202][202][512] fp32 (zero-padded)
__global__ void k_feat_px(const float* __restrict__ feat, float* __restrict__ feat_px) {
    __shared__ float lt[32 * 8 * 33];
    int x0 = blockIdx.x * 32, y0 = blockIdx.y * 8, ci0 = blockIdx.z * 32;
    int tid = threadIdx.x;
    for (int u = tid; u < 8192; u += 256) {
        int ciL = u >> 8, rem = u & 255;
        int yy = rem >> 5, xx = rem & 31;
        int x = x0 + xx;
        float v = (x < W_) ? feat[(size_t)(ci0 + ciL) * HW_ + (y0 + yy) * W_ + x] : 0.f;
        lt[(ciL * 8 + yy) * 33 + xx] = v;
    }
    __syncthreads();
    for (int u = tid; u < 1024; u += 256) {
        int pxu = u >> 2, part = u & 3;
        int yy = pxu >> 5, xx = pxu & 31;
        if (x0 + xx >= W_) continue;
        float tmp[8];
#pragma unroll
        for (int k = 0; k < 8; ++k) tmp[k] = lt[((part * 8 + k) * 8 + yy) * 33 + xx];
        float* dst = &feat_px[((size_t)(y0 + yy + 1) * FP + (x0 + xx + 1)) * 512 + ci0 + part * 8];
        *(float4*)&dst[0] = *(const float4*)&tmp[0];
        *(float4*)&dst[4] = *(const float4*)&tmp[4];
    }
}

// ---------------------------------------------------------------------------
// FUSED weight transforms: one strided read of conv_w produces
//   wt_t  [tap9][co512][ci512] bf16  (write coalesced in ci)
//   wt_ex [k'=tap*512+ci][co512] f32 (LDS-transposed write)
// (was two kernels, each doing the stride-36B gather of conv_w)
// ---------------------------------------------------------------------------
__global__ void k_wt_both(const float* __restrict__ conv_w, ushort* __restrict__ wt_t,
                          float* __restrict__ wt_ex) {
    __shared__ float t[32][33];
    int kb = blockIdx.x * 32;   // k' base (4608/32 = 144), single tap per tile
    int cb = blockIdx.y * 32;
    int lx = threadIdx.x, ly = threadIdx.y;
    int tap = kb >> 9, ci0 = kb & 511;
    for (int r = ly; r < 32; r += 8) {
        float v = conv_w[((size_t)(cb + r) * 512 + ci0 + lx) * 9 + tap];
        t[r][lx] = v;
        wt_t[(size_t)tap * 262144 + (size_t)(cb + r) * 512 + ci0 + lx] = f2bf(v);
    }
    __syncthreads();
    for (int r = ly; r < 32; r += 8)
        wt_ex[(size_t)(kb + r) * 512 + cb + lx] = t[lx][r];
}

// ---------------------------------------------------------------------------
// Approx conv v5 (207us): bf16 MFMA 16x16x32. Block = 64 co x (16x32 px),
// 4 waves, acc[4 pi][2 xh][4 cj]. XCD swizzle, global_load_lds staging.
// ---------------------------------------------------------------------------
__global__ __launch_bounds__(256)
__attribute__((amdgpu_waves_per_eu(2, 4)))
void k_conv3_mfma(const ushort* __restrict__ feat_t, const ushort* __restrict__ wt_t,
                  const float* __restrict__ bias, ushort* __restrict__ xab) {
    __shared__ ushort halo[18 * 34 * 32];   // [r][c34][32ci] 39.2 KB (linear = unit*16B)
    __shared__ ushort wtile[9 * 64 * 32];   // [tap][co][32ci] 36.9 KB (linear)
    int b = blockIdx.x;
    int cot = b & 7;            // XCD-aligned co-slice (728 = 8 x 91, bijective)
    int tile = b >> 3;          // 0..90
    int xt = tile % 7, yt = tile / 7;
    int x0 = xt * 32, y0 = yt * 16;
    int co0 = cot * 64;
    int tid = threadIdx.x;
    int lane = tid & 63, wid = tid >> 6;
    int l15 = lane & 15, l4 = lane >> 4;

    f32x4 acc[4][2][4];
#pragma unroll
    for (int i = 0; i < 4; ++i)
#pragma unroll
        for (int h = 0; h < 2; ++h)
#pragma unroll
            for (int j = 0; j < 4; ++j) acc[i][h][j] = (f32x4){0.f, 0.f, 0.f, 0.f};

    for (int ch = 0; ch < 16; ++ch) {
        int ci0 = ch * 32;
        __syncthreads();   // previous chunk's LDS reads done
        for (int u = tid; u < 2448; u += 256) {
            int p = u >> 2, q = u & 3;
            int r = p / 34, c = p - r * 34;
            const ushort* src = feat_t + ((size_t)(y0 + r) * FT + (x0 + c)) * 512 + ci0 + q * 8;
            gload_lds16(src, &halo[(u & ~63) * 8]);
        }
        for (int u = tid; u < 2304; u += 256) {
            int row = u >> 2, q = u & 3;       // row = tap*64 + co
            int tap = row >> 6, co = row & 63;
            const ushort* src = wt_t + ((size_t)(tap * 512 + co0 + co)) * 512 + ci0 + q * 8;
            gload_lds16(src, &wtile[(u & ~63) * 8]);
        }
        __syncthreads();   // drains vmcnt -> LDS valid
#pragma unroll
        for (int tap = 0; tap < 9; ++tap) {
            int th = tap / 3, tw = tap - th * 3;
            bf16x8 af[4][2];
#pragma unroll
            for (int pi = 0; pi < 4; ++pi)
#pragma unroll
                for (int xh = 0; xh < 2; ++xh)
                    af[pi][xh] = *(const bf16x8*)&halo[
                        ((wid * 4 + pi + th) * 34 + (xh * 16 + l15 + tw)) * 32 + l4 * 8];
#pragma unroll
            for (int cj = 0; cj < 4; ++cj) {
                bf16x8 bf = *(const bf16x8*)&wtile[(tap * 64 + cj * 16 + l15) * 32 + l4 * 8];
#pragma unroll
                for (int pi = 0; pi < 4; ++pi)
#pragma unroll
                    for (int xh = 0; xh < 2; ++xh)
                        acc[pi][xh][cj] = __builtin_amdgcn_mfma_f32_16x16x32_bf16(
                            af[pi][xh], bf, acc[pi][xh][cj], 0, 0, 0);
            }
        }
    }

    float bv[4];
#pragma unroll
    for (int cj = 0; cj < 4; ++cj) bv[cj] = bias[co0 + cj * 16 + l15];
#pragma unroll
    for (int pi = 0; pi < 4; ++pi) {
        int yy = y0 + wid * 4 + pi;
        if (yy >= H_) continue;
#pragma unroll
        for (int xh = 0; xh < 2; ++xh) {
#pragma unroll
            for (int cj = 0; cj < 4; ++cj) {
                int co = co0 + cj * 16 + l15;
#pragma unroll
                for (int r = 0; r < 4; ++r) {
                    int xx = x0 + xh * 16 + l4 * 4 + r;
                    if (xx < W_) {
                        float v = acc[pi][xh][cj][r] + bv[cj];
                        xab[((size_t)(yy * W_ + xx)) * 512 + co] = f2bf(v > 0.f ? v : 0.f);
                    }
                }
            }
        }
    }
}

// ---------------------------------------------------------------------------
// Approx cls (shuffle-free): 64 px/block x 64 threads; LDS x-tile; thread owns
// a px, walks co serially; cls_w reads wave-uniform (scalar loads).
// ---------------------------------------------------------------------------
__global__ void k_cls(const ushort* __restrict__ xab, const float* __restrict__ cls_w,
                      const float* __restrict__ cls_b, float* __restrict__ scores) {
    __shared__ ushort xt[64 * 520];        // 65 KB, row stride 1040B (16B-aligned)
    int t = threadIdx.x;                   // 64 threads
    int pxb = blockIdx.x * 64;
    for (int i = 0; i < 64; ++i)
        *(uint4*)&xt[i * 520 + t * 8] =
            *(const uint4*)&xab[((size_t)(pxb + i)) * 512 + t * 8];
    __syncthreads();
    float acc[9];
#pragma unroll
    for (int a = 0; a < 9; ++a) acc[a] = 0.f;
    const ushort* row = &xt[t * 520];
    for (int k = 0; k < 64; ++k) {
        bf16x8 v = *(const bf16x8*)&row[k * 8];
        float xv[8];
#pragma unroll
        for (int j = 0; j < 8; ++j) xv[j] = bf2f((ushort)v[j]);
#pragma unroll
        for (int a = 0; a < 9; ++a)
#pragma unroll
            for (int j = 0; j < 8; ++j)
                acc[a] = fmaf(xv[j], cls_w[a * 512 + k * 8 + j], acc[a]);
    }
    int px = pxb + t;
#pragma unroll
    for (int a = 0; a < 9; ++a)
        scores[(size_t)px * 9 + a] = 1.f / (1.f + expf(-(acc[a] + cls_b[a])));
}

// ---------------------------------------------------------------------------
// Radix-select helpers
// meta: [0]=P [1]=cntAboveP [2]=T [3]=cntGtT [4]=need [8]=atomGt [9]=atomEq [10]=npx
// ---------------------------------------------------------------------------
__global__ void k_hist1_lds(const float* __restrict__ scores, unsigned* __restrict__ hist) {
    __shared__ unsigned h[16384];
    int tid = threadIdx.x;
    for (int j = tid; j < 16384; j += 256) h[j] = 0u;
    __syncthreads();
    int stride = gridDim.x * 256;
    for (int i = blockIdx.x * 256 + tid; i < NANCH; i += stride)
        atomicAdd(&h[(__float_as_uint(scores[i]) >> 16) & 16383], 1u);
    __syncthreads();
    for (int j = tid; j < 16384; j += 256) {
        unsigned v = h[j];
        if (v) atomicAdd(&hist[j], v);
    }
}

__global__ void k_find_thr(const unsigned* __restrict__ hist, unsigned* __restrict__ meta,
                           int mode, int Kwant) {
    __shared__ unsigned csum[1024];
    int t = threadIdx.x;
    unsigned base = (mode == 0) ? 0u : meta[1];
    unsigned s = 0;
    for (int b = 0; b < 64; ++b) s += hist[t * 64 + b];
    csum[t] = s;
    __syncthreads();
    for (int off = 1; off < 1024; off <<= 1) {
        unsigned add = (t + off < 1024) ? csum[t + off] : 0u;
        __syncthreads();
        csum[t] += add;
        __syncthreads();
    }
    unsigned run = base + ((t < 1023) ? csum[t + 1] : 0u);
    for (int b = 63; b >= 0; --b) {
        unsigned h = hist[t * 64 + b];
        if (run < (unsigned)Kwant && run + h >= (unsigned)Kwant) {
            if (mode == 0) {
                meta[0] = (unsigned)(t * 64 + b);
                meta[1] = run;
            } else {
                meta[2] = (meta[0] << 16) | (unsigned)(t * 64 + b);
                meta[3] = run;
                meta[4] = (unsigned)Kwant - run;
            }
            break;
        }
        run += h;
    }
}

// mark candidate pixels: anchors with hi16(score) >= P
__global__ void k_collect_cand(const float* __restrict__ scores, const unsigned* __restrict__ meta,
                               unsigned* __restrict__ flags) {
    int i = blockIdx.x * 256 + threadIdx.x;
    if (i >= NANCH) return;
    if ((__float_as_uint(scores[i]) >> 16) >= meta[0]) flags[i / 9] = 1u;
}

__global__ void k_px_compact(unsigned* __restrict__ flags, unsigned* __restrict__ meta,
                             unsigned* __restrict__ px_list) {
    int px = blockIdx.x * 256 + threadIdx.x;
    if (px >= HW_) return;
    if (flags[px]) {
        unsigned s = atomicAdd(&meta[10], 1u);
        if (s < (unsigned)PXCAP) { px_list[s] = (unsigned)px; flags[px] = s + 1u; }
        else flags[px] = 0u;
    }
}

// ---------------------------------------------------------------------------
// Exact fp32 conv GEMM v5: C[64co x 64px], K split x8 (576 each). 64-k LDS
// staging (two 32-halves handle the tap boundary; 512%32==0 so each half is
// within one tap) -> barriers 36 -> 18 per block. Same accumulation order as
// v4 (k ascending) -> bit-identical xpart.
// ---------------------------------------------------------------------------
__global__ __attribute__((amdgpu_waves_per_eu(2, 4)))
void k_exact_gemm(const float* __restrict__ feat_px, const float* __restrict__ wt_ex,
                  const unsigned* __restrict__ meta, const unsigned* __restrict__ px_list,
                  float* __restrict__ xpart) {
    int npx = (int)meta[10]; if (npx > PXCAP) npx = PXCAP;
    int pb = blockIdx.x;
    if (pb * 64 >= npx) return;
    int cot = blockIdx.y;           // 0..7 -> 64 co
    int kz = blockIdx.z;            // 0..7 -> K = 576
    __shared__ float A[64][68];
    __shared__ float B[64][68];
    __shared__ int plist[64];
    int tid = threadIdx.x;
    int co0 = cot * 64;
    if (tid < 64) {
        int slot = pb * 64 + tid;
        plist[tid] = (slot < npx) ? (int)px_list[slot] : (int)px_list[0];
    }
    int tcog = tid >> 4;   // 16 groups x 4 co
    int tpxg = tid & 15;   // 16 groups x 4 px
    float acc[4][4];
#pragma unroll
    for (int i = 0; i < 4; ++i)
#pragma unroll
        for (int j = 0; j < 4; ++j) acc[i][j] = 0.f;
    int kbase = kz * 576;
    for (int kc = 0; kc < 9; ++kc) {
        int k0 = kbase + kc * 64;
        __syncthreads();                                 // covers plist on kc==0
        for (int u = tid; u < 1024; u += 256) {          // A: 64k x 64co from wt_ex
            int k = u >> 4, cp = (u & 15) * 4;
            *(float4*)&A[k][cp] = *(const float4*)&wt_ex[(size_t)(k0 + k) * 512 + co0 + cp];
        }
#pragma unroll
        for (int hh = 0; hh < 2; ++hh) {                 // B: two 32-k halves
            int kh = k0 + hh * 32;
            int tap = kh >> 9, ci0c = kh & 511;
            int th = tap / 3, tw = tap - th * 3;
            for (int u = tid; u < 512; u += 256) {
                int s = u >> 3, part = u & 7;
                int px = plist[s];
                int y = px / W_, x = px - y * W_;
                float4 v = *(const float4*)&feat_px[((size_t)(y + th) * FP + (x + tw)) * 512 + ci0c + part * 4];
                B[hh * 32 + part * 4 + 0][s] = v.x; B[hh * 32 + part * 4 + 1][s] = v.y;
                B[hh * 32 + part * 4 + 2][s] = v.z; B[hh * 32 + part * 4 + 3][s] = v.w;
            }
        }
        __syncthreads();
#pragma unroll 4
        for (int k = 0; k < 64; ++k) {
            float wv[4], pv[4];
            *(float4*)&wv[0] = *(const float4*)&A[k][tcog * 4];
            *(float4*)&pv[0] = *(const float4*)&B[k][tpxg * 4];
#pragma unroll
            for (int i = 0; i < 4; ++i)
#pragma unroll
                for (int j = 0; j < 4; ++j) acc[i][j] = fmaf(wv[i], pv[j], acc[i][j]);
        }
    }
#pragma unroll
    for (int j = 0; j < 4; ++j) {
        int slot = pb * 64 + tpxg * 4 + j;
        if (slot >= npx) continue;
        f32x4 tmp;
        tmp[0] = acc[0][j]; tmp[1] = acc[1][j]; tmp[2] = acc[2][j]; tmp[3] = acc[3][j];
        __builtin_nontemporal_store(tmp,
            (f32x4*)&xpart[((size_t)kz * PXCAP + slot) * 512 + co0 + tcog * 4]);
    }
}

// ---------------------------------------------------------------------------
// MERGED exact finalize: fixed-order K-split reduce + bias + relu -> xex,
// then the 9 exact anchor scores (same fma/shuffle trees as before ->
// bit-identical to the old reduce+scores pair).
// ---------------------------------------------------------------------------
__global__ void k_exact_fin(const float* __restrict__ xpart, const float* __restrict__ bias,
                            const float* __restrict__ cls_w, const float* __restrict__ cls_b,
                            const unsigned* __restrict__ meta,
                            float* __restrict__ xex, float* __restrict__ scores_ex) {
    int slot = blockIdx.x;
    int npx = (int)meta[10]; if (npx > PXCAP) npx = PXCAP;
    if (slot >= npx) return;
    int l = threadIdx.x;               // 64
    float xv[8];
#pragma unroll
    for (int j = 0; j < 8; ++j) {
        int co = j * 64 + l;
        float v = 0.f;
#pragma unroll
        for (int kz = 0; kz < KSPLIT; ++kz)
            v += __builtin_nontemporal_load(&xpart[((size_t)kz * PXCAP + slot) * 512 + co]);
        v += bias[co];
        v = v > 0.f ? v : 0.f;
        xex[(size_t)slot * 512 + co] = v;
        xv[j] = v;
    }
#pragma unroll
    for (int a = 0; a < 9; ++a) {
        float s = 0.f;
#pragma unroll
        for (int k = 0; k < 8; ++k) s = fmaf(xv[k], cls_w[a * 512 + k * 64 + l], s);
#pragma unroll
        for (int o = 32; o > 0; o >>= 1) s += __shfl_down(s, o);
        if (l == 0) scores_ex[slot * 9 + a] = 1.f / (1.f + expf(-(s + cls_b[a])));
    }
}

__global__ void k_hist1_ex_lds(const float* __restrict__ scores_ex, const unsigned* __restrict__ meta,
                               unsigned* __restrict__ hist) {
    __shared__ unsigned h[16384];
    int npx = (int)meta[10]; if (npx > PXCAP) npx = PXCAP;
    int n = npx * 9;
    int tid = threadIdx.x;
    for (int j = tid; j < 16384; j += 256) h[j] = 0u;
    __syncthreads();
    for (int i = blockIdx.x * 256 + tid; i < n; i += 32 * 256)
        atomicAdd(&h[(__float_as_uint(scores_ex[i]) >> 16) & 16383], 1u);
    __syncthreads();
    for (int j = tid; j < 16384; j += 256) {
        unsigned v = h[j];
        if (v) atomicAdd(&hist[j], v);
    }
}

__global__ void k_hist2_ex(const float* __restrict__ scores_ex, const unsigned* __restrict__ meta,
                           const unsigned* __restrict__ meta_ex, unsigned* __restrict__ hist2) {
    int npx = (int)meta[10]; if (npx > PXCAP) npx = PXCAP;
    int i = blockIdx.x * 256 + threadIdx.x;
    if (i >= npx * 9) return;
    unsigned b = __float_as_uint(scores_ex[i]);
    if ((b >> 16) == meta_ex[0]) atomicAdd(&hist2[b & 0xFFFFu], 1u);
}

__global__ void k_collect_ex(const float* __restrict__ scores_ex, const unsigned* __restrict__ meta,
                             unsigned* __restrict__ meta_ex, const unsigned* __restrict__ px_list,
                             unsigned* __restrict__ sel_bits, unsigned* __restrict__ sel_idx,
                             unsigned* __restrict__ eq_idx) {
    int npx = (int)meta[10]; if (npx > PXCAP) npx = PXCAP;
    int i = blockIdx.x * 256 + threadIdx.x;
    if (i >= npx * 9) return;
    unsigned b = __float_as_uint(scores_ex[i]);
    unsigned T = meta_ex[2];
    unsigned g = px_list[i / 9] * 9u + (unsigned)(i % 9);
    if (b > T) {
        unsigned s = atomicAdd(&meta_ex[8], 1u);
        if (s < 1024u) { sel_bits[s] = b; sel_idx[s] = g; }
    } else if (b == T) {
        unsigned s = atomicAdd(&meta_ex[9], 1u);
        if (s < 65536u) eq_idx[s] = g;
    }
}

// exact stable top-1000 (ties -> smallest global idx), bitonic final order
__global__ void k_topk_final(const unsigned* __restrict__ sel_bits, const unsigned* __restrict__ sel_idx,
                             const unsigned* __restrict__ eq_idx, const unsigned* __restrict__ meta,
                             unsigned* __restrict__ top_idx, float* __restrict__ top_sc) {
    __shared__ uint64_t keys[1024];
    __shared__ int lcnt;
    __shared__ int lred;
    int t = threadIdx.x;
    unsigned cntGt = meta[3];
    unsigned need = meta[4];
    unsigned cntEq = meta[9];
    unsigned T = meta[2];

    unsigned idx_cut = 0xFFFFFFFFu;
    if (cntEq > need) {
        unsigned lo = 0, hi = NANCH - 1;
        while (lo < hi) {
            unsigned mid = (lo + hi) >> 1;
            int c = 0;
            for (unsigned e = t; e < cntEq; e += 1024)
                if (eq_idx[e] <= mid) c++;
            if (t == 0) lred = 0;
            __syncthreads();
            atomicAdd(&lred, c);
            __syncthreads();
            int tot = lred;
            __syncthreads();
            if ((unsigned)tot >= need) hi = mid; else lo = mid + 1;
        }
        idx_cut = lo;
    }

    keys[t] = 0ull;
    if (t == 0) lcnt = 0;
    __syncthreads();
    for (unsigned s = t; s < cntGt; s += 1024)
        keys[s] = ((uint64_t)sel_bits[s] << 32) | (uint64_t)(0xFFFFFFFFu - sel_idx[s]);
    for (unsigned e = t; e < cntEq; e += 1024) {
        unsigned ix = eq_idx[e];
        if (ix <= idx_cut) {
            int s2 = (int)cntGt + atomicAdd(&lcnt, 1);
            keys[s2] = ((uint64_t)T << 32) | (uint64_t)(0xFFFFFFFFu - ix);
        }
    }
    __syncthreads();
    for (int k = 2; k <= 1024; k <<= 1) {
        for (int j = k >> 1; j > 0; j >>= 1) {
            int ixj = t ^ j;
            if (ixj > t) {
                uint64_t a = keys[t], b = keys[ixj];
                bool desc = (t & k) == 0;
                if (desc ? (a < b) : (a > b)) { keys[t] = b; keys[ixj] = a; }
            }
            __syncthreads();
        }
    }
    if (t < KPRE) {
        top_sc[t] = __uint_as_float((unsigned)(keys[t] >> 32));
        top_idx[t] = 0xFFFFFFFFu - (unsigned)keys[t];
    }
}

// ---------------------------------------------------------------------------
// decode from exact x (via flags px->slot map)
// ---------------------------------------------------------------------------
__global__ void k_decode(const float* __restrict__ xex, const unsigned* __restrict__ flags,
                         const float* __restrict__ reg_w, const float* __restrict__ reg_b,
                         const unsigned* __restrict__ top_idx,
                         float* __restrict__ props, float* __restrict__ areas) {
    int j = blockIdx.x;
    int lane = threadIdx.x;  // 64
    unsigned idx = top_idx[j];
    int pix = (int)(idx / 9u);
    int a = (int)(idx - (unsigned)pix * 9u);
    int slot = (int)flags[pix] - 1;
    if (slot < 0) slot = 0;
    const float* xr = xex + (size_t)slot * 512;
    float s0 = 0, s1 = 0, s2 = 0, s3 = 0;
    for (int c = lane; c < C_; c += 64) {
        float xv = xr[c];
        s0 = fmaf(xv, reg_w[(a * 4 + 0) * C_ + c], s0);
        s1 = fmaf(xv, reg_w[(a * 4 + 1) * C_ + c], s1);
        s2 = fmaf(xv, reg_w[(a * 4 + 2) * C_ + c], s2);
        s3 = fmaf(xv, reg_w[(a * 4 + 3) * C_ + c], s3);
    }
#pragma unroll
    for (int o = 32; o > 0; o >>= 1) {
        s0 += __shfl_down(s0, o);
        s1 += __shfl_down(s1, o);
        s2 += __shfl_down(s2, o);
        s3 += __shfl_down(s3, o);
    }
    if (lane == 0) {
        float d0 = s0 + reg_b[a * 4 + 0];
        float d1 = s1 + reg_b[a * 4 + 1];
        float d2 = s2 + reg_b[a * 4 + 2];
        float d3 = s3 + reg_b[a * 4 + 3];
        int h = pix / W_, w2 = pix - h * W_;
        int rr = a / 3, ss = a - rr * 3;
        float ratio = (rr == 0) ? 0.5f : (rr == 1) ? 1.0f : 2.0f;
        float scale = (ss == 0) ? 128.f : (ss == 1) ? 256.f : 512.f;
        float hr = sqrtf(ratio);
        float wr = 1.0f / hr;
        float wsc = wr * scale, hsc = hr * scale;
        float sx = (float)w2 * 16.f, sy = (float)h * 16.f;
        float a0 = sx - wsc * 0.5f, a1 = sy - hsc * 0.5f;
        float a2 = sx + wsc * 0.5f, a3 = sy + hsc * 0.5f;
        float bw = a2 - a0, bh = a3 - a1;
        float cx = a0 + 0.5f * bw, cy = a1 + 0.5f * bh;
        float px = d0 * bw + cx, py = d1 * bh + cy;
        float pw = expf(d2) * bw, ph = expf(d3) * bh;
        float b0 = px - 0.5f * pw, b1 = py - 0.5f * ph;
        float b2 = px + 0.5f * pw, b3 = py + 0.5f * ph;
        b0 = fminf(fmaxf(b0, 0.f), 3200.f);
        b1 = fminf(fmaxf(b1, 0.f), 3200.f);
        b2 = fminf(fmaxf(b2, 0.f), 3200.f);
        b3 = fminf(fmaxf(b3, 0.f), 3200.f);
        props[j * 4 + 0] = b0;
        props[j * 4 + 1] = b1;
        props[j * 4 + 2] = b2;
        props[j * 4 + 3] = b3;
        areas[j] = (b2 - b0) * (b3 - b1);
    }
}

// ---------------------------------------------------------------------------
__global__ void k_nms_mask(const float* __restrict__ props, const float* __restrict__ areas,
                           unsigned long long* __restrict__ mask, float* __restrict__ out) {
    int i = blockIdx.x;
    int tid = threadIdx.x;  // 256
    if (i == 0) {
        for (int t = tid; t < KPOST * 5; t += 256) out[t] = 0.f;
    }
    float x1i = props[i * 4 + 0], y1i = props[i * 4 + 1];
    float x2i = props[i * 4 + 2], y2i = props[i * 4 + 3];
    float ai = areas[i];
#pragma unroll
    for (int k = 0; k < 4; ++k) {
        int j = k * 256 + tid;
        bool sup = false;
        if (j < KPRE && j > i) {
            float iw = fminf(x2i, props[j * 4 + 2]) - fmaxf(x1i, props[j * 4 + 0]);
            float ih = fminf(y2i, props[j * 4 + 3]) - fmaxf(y1i, props[j * 4 + 1]);
            iw = fmaxf(iw, 0.f);
            ih = fmaxf(ih, 0.f);
            float inter = iw * ih;
            float iou = inter / (ai + areas[j] - inter);
            sup = iou > 0.7f;
        }
        unsigned long long b = __ballot(sup);
        int word = k * 4 + (tid >> 6);
        if ((tid & 63) == 0) mask[(size_t)i * 16 + word] = b;
    }
}

// ---------------------------------------------------------------------------
// NMS scan: kept-box iteration with early exit at 100 kept.
// ---------------------------------------------------------------------------
__global__ void k_nms_scan_out(const unsigned long long* __restrict__ mask,
                               const float* __restrict__ props, const float* __restrict__ top_sc,
                               float* __restrict__ out) {
    __shared__ int kidx[KPOST];
    __shared__ int nk;
    int lane = threadIdx.x;  // 64
    if (lane == 0) {
        unsigned long long k0 = ~0ull, k1 = ~0ull, k2 = ~0ull, k3 = ~0ull;
        unsigned long long k4 = ~0ull, k5 = ~0ull, k6 = ~0ull, k7 = ~0ull;
        unsigned long long k8 = ~0ull, k9 = ~0ull, k10 = ~0ull, k11 = ~0ull;
        unsigned long long k12 = ~0ull, k13 = ~0ull, k14 = ~0ull;
        unsigned long long k15 = (1ull << 40) - 1ull;   // 1000 bits total
        int kept = 0;
#define APPLY_ROW(ii) { const unsigned long long* row = &mask[(size_t)(ii) * 16];          \
        k0 &= ~row[0];  k1 &= ~row[1];  k2 &= ~row[2];  k3 &= ~row[3];                     \
        k4 &= ~row[4];  k5 &= ~row[5];  k6 &= ~row[6];  k7 &= ~row[7];                     \
        k8 &= ~row[8];  k9 &= ~row[9];  k10 &= ~row[10]; k11 &= ~row[11];                  \
        k12 &= ~row[12]; k13 &= ~row[13]; k14 &= ~row[14]; k15 &= ~row[15]; }
#define SCAN_WORD(w, kw) { \
        unsigned long long rem = kw; \
        while (rem) { \
            int b = __builtin_ctzll(rem); \
            kidx[kept++] = (w) * 64 + b; \
            if (kept == KPOST) goto done; \
            APPLY_ROW((w) * 64 + b); \
            rem &= kw; \
            rem &= (b >= 63) ? 0ull : ~((2ull << b) - 1ull); \
        } }
        SCAN_WORD(0, k0)  SCAN_WORD(1, k1)  SCAN_WORD(2, k2)  SCAN_WORD(3, k3)
        SCAN_WORD(4, k4)  SCAN_WORD(5, k5)  SCAN_WORD(6, k6)  SCAN_WORD(7, k7)
        SCAN_WORD(8, k8)  SCAN_WORD(9, k9)  SCAN_WORD(10, k10) SCAN_WORD(11, k11)
        SCAN_WORD(12, k12) SCAN_WORD(13, k13) SCAN_WORD(14, k14) SCAN_WORD(15, k15)
done:
        nk = kept;
#undef SCAN_WORD
#undef APPLY_ROW
    }
    __syncthreads();
    int n = nk;
    for (int t = lane; t < KPOST; t += 64) {
        if (t < n) {
            int i = kidx[t];
            out[t * 4 + 0] = props[i * 4 + 0];
            out[t * 4 + 1] = props[i * 4 + 1];
            out[t * 4 + 2] = props[i * 4 + 2];
            out[t * 4 + 3] = props[i * 4 + 3];
            out[KPOST * 4 + t] = top_sc[i];
        }
    }
}

// ---------------------------------------------------------------------------
extern "C" void kernel_launch(void* const* d_in, const int* in_sizes, int n_in,
                              void* d_out, int out_size, void* d_ws, size_t ws_size,
                              hipStream_t stream) {
    const float* feat   = (const float*)d_in[0];
    const float* conv_w = (const float*)d_in[1];
    const float* conv_b = (const float*)d_in[2];
    const float* cls_w  = (const float*)d_in[3];
    const float* cls_b  = (const float*)d_in[4];
    const float* reg_w  = (const float*)d_in[5];
    const float* reg_b  = (const float*)d_in[6];
    float* out = (float*)d_out;

    size_t off = 0;
    auto alloc = [&](size_t bytes) -> void* {
        off = (off + 255) & ~(size_t)255;
        void* p = (char*)d_ws + off;
        off += bytes;
        return p;
    };
    ushort* feat_t  = (ushort*)alloc((size_t)FT * FT * 512 * 2);        // 46.0 MB
    float*  feat_px = (float*)alloc((size_t)FP * FP * 512 * 4);         // 83.6 MB
    ushort* wt_t    = (ushort*)alloc((size_t)9 * 512 * 512 * 2);        // 4.7 MB
    float*  wt_ex   = (float*)alloc((size_t)9 * 512 * 512 * 4);         // 9.4 MB
    ushort* xab     = (ushort*)alloc((size_t)HW_ * 512 * 2);            // 41 MB
    float*  xpart   = (float*)alloc((size_t)KSPLIT * PXCAP * 512 * 4);  // 67 MB
    float*  xex     = (float*)alloc((size_t)PXCAP * 512 * 4);           // 8.4 MB
    float*  scores  = (float*)alloc((size_t)NANCH * 4);                 // 1.44 MB
    float*  scores_ex = (float*)alloc((size_t)PXCAP * 9 * 4);
    // contiguous zero region: hist1, hist2, hist1e, hist2e, meta, meta_ex, flags
    unsigned* hist1   = (unsigned*)alloc(65536 * 4);
    unsigned* hist2   = (unsigned*)alloc(65536 * 4);
    unsigned* hist1e  = (unsigned*)alloc(65536 * 4);
    unsigned* hist2e  = (unsigned*)alloc(65536 * 4);
    unsigned* meta    = (unsigned*)alloc(64 * 4);
    unsigned* meta_ex = (unsigned*)alloc(64 * 4);
    unsigned* flags   = (unsigned*)alloc((size_t)HW_ * 4);
    unsigned* px_list = (unsigned*)alloc(PXCAP * 4);
    unsigned* sel_bits = (unsigned*)alloc(1024 * 4);
    unsigned* sel_idx  = (unsigned*)alloc(1024 * 4);
    unsigned* eq_idx   = (unsigned*)alloc(65536 * 4);
    unsigned* top_idx  = (unsigned*)alloc(KPRE * 4);
    float* top_sc      = (float*)alloc(KPRE * 4);
    float* props       = (float*)alloc(KPRE * 4 * 4);
    float* areas       = (float*)alloc(KPRE * 4);
    unsigned long long* mask = (unsigned long long*)alloc((size_t)KPRE * 16 * 8);
    (void)ws_size; (void)in_sizes; (void)n_in; (void)out_size;

    // 0) prep for APPROX path (feat_px deferred to keep feat_t/wt_t L3-warm);
    //    single upfront zero of all hist/meta/flags
    k_zero_border_t<<<(4944 * 64 + 255) / 256, 256, 0, stream>>>(feat_t);
    int zrDw = 65536 * 4 + 128 + HW_;
    k_zero_u32<<<(zrDw + 255) / 256, 256, 0, stream>>>(hist1, zrDw);
    k_feat_t<<<dim3(7, 25, 16), 256, 0, stream>>>(feat, feat_t);
    k_wt_both<<<dim3(144, 16), dim3(32, 8), 0, stream>>>(conv_w, wt_t, wt_ex);
    // 1) approx conv (bf16 MFMA) + approx cls
    k_conv3_mfma<<<8 * 91, 256, 0, stream>>>(feat_t, wt_t, conv_b, xab);
    k_cls<<<HW_ / 64, 64, 0, stream>>>(xab, cls_w, cls_b, scores);
    // 2) candidate pixels: approx top-KSEL bucket threshold (LDS hist)
    k_hist1_lds<<<64, 256, 0, stream>>>(scores, hist1);
    k_find_thr<<<1, 1024, 0, stream>>>(hist1, meta, 0, KSEL);
    k_collect_cand<<<(NANCH + 255) / 256, 256, 0, stream>>>(scores, meta, flags);
    k_px_compact<<<(HW_ + 255) / 256, 256, 0, stream>>>(flags, meta, px_list);
    // 2b) exact-path feature layout (deferred from step 0)
    k_zero_border_px<<<(804 * 128 + 255) / 256, 256, 0, stream>>>(feat_px);
    k_feat_px<<<dim3(7, 25, 16), 256, 0, stream>>>(feat, feat_px);
    // 3) exact fp32 conv at candidates: K-split GEMM -> merged finalize
    k_exact_gemm<<<dim3(PXCAP / 64, 8, KSPLIT), 256, 0, stream>>>(feat_px, wt_ex, meta, px_list, xpart);
    k_exact_fin<<<PXCAP, 64, 0, stream>>>(xpart, conv_b, cls_w, cls_b, meta, xex, scores_ex);
    // 4) exact stable top-1000 among candidate anchors (global indices)
    k_hist1_ex_lds<<<32, 256, 0, stream>>>(scores_ex, meta, hist1e);
    k_find_thr<<<1, 1024, 0, stream>>>(hist1e, meta_ex, 0, KPRE);
    k_hist2_ex<<<(PXCAP * 9 + 255) / 256, 256, 0, stream>>>(scores_ex, meta, meta_ex, hist2e);
    k_find_thr<<<1, 1024, 0, stream>>>(hist2e, meta_ex, 1, KPRE);
    k_collect_ex<<<(PXCAP * 9 + 255) / 256, 256, 0, stream>>>(scores_ex, meta, meta_ex, px_list,
                                                              sel_bits, sel_idx, eq_idx);
    k_topk_final<<<1, 1024, 0, stream>>>(sel_bits, sel_idx, eq_idx, meta_ex, top_idx, top_sc);
    // 5) exact decode + NMS
    k_decode<<<KPRE, 64, 0, stream>>>(xex, flags, reg_w, reg_b, top_idx, props, areas);
    k_nms_mask<<<KPRE, 256, 0, stream>>>(props, areas, mask, out);
    k_nms_scan_out<<<1, 64, 0, stream>>>(mask, props, top_sc, out);
}

// Round 16
// 609.970 us; speedup vs baseline: 1.1635x; 1.1635x over previous
//
#include <hip/hip_runtime.h>
#include <stdint.h>

// Problem constants
static constexpr int H_ = 200, W_ = 200, HW_ = 40000;
static constexpr int C_ = 512;
static constexpr int NANCH = 360000;   // HW_ * 9
static constexpr int KPRE = 1000;
static constexpr int KPOST = 100;
static constexpr int KSEL = 1400;      // approx candidate margin (top-1000 + 400)
static constexpr int PXCAP = 4096;     // candidate pixel cap (est npx ~1600)
static constexpr int KSPLIT = 8;       // exact-gemm K split (4608 = 8 x 576)
static constexpr int FT = 212;         // feat_t padded dim, (y,x) real at +1
static constexpr int FP = 202;         // feat_px padded dim, (y,x) real at +1

typedef __attribute__((ext_vector_type(8))) short bf16x8;
typedef __attribute__((ext_vector_type(4))) float f32x4;

__device__ inline ushort f2bf(float f) {               // RNE float->bf16 bits
    unsigned u = __float_as_uint(f);
    u += 0x7FFFu + ((u >> 16) & 1u);
    return (ushort)(u >> 16);
}
__device__ inline float bf2f(ushort h) { return __uint_as_float(((unsigned)h) << 16); }

// async global->LDS 16B: per-lane global src, LDS dst = wave-uniform base + lane*16
typedef const __attribute__((address_space(1))) uint32_t gas_u32;
typedef __attribute__((address_space(3))) uint32_t las_u32;
__device__ __forceinline__ void gload_lds16(const void* g, void* l) {
    __builtin_amdgcn_global_load_lds((gas_u32*)(uintptr_t)g, (las_u32*)(uintptr_t)l, 16, 0, 0);
}

// ---------------------------------------------------------------------------
__global__ void k_zero_u32(unsigned* __restrict__ p, int n) {
    int i = blockIdx.x * 256 + threadIdx.x;
    if (i < n) p[i] = 0u;
}

// Border-only zeroing (interiors fully overwritten by k_feat_both).
__global__ void k_zero_border_t(ushort* __restrict__ feat_t) {
    int t = blockIdx.x * 256 + threadIdx.x;
    int total = 4944 * 64;           // 512 bf16 = 64 x uint4 per px
    if (t >= total) return;
    int px = t >> 6, part = t & 63;
    int y, x;
    if (px < 2544) { int ri = px / 212; x = px - ri * 212; y = (ri == 0) ? 0 : 200 + ri; }
    else { int q = px - 2544; int r12 = q / 12; int c = q - r12 * 12; y = 1 + r12; x = (c == 0) ? 0 : 200 + c; }
    uint4 z = {0u, 0u, 0u, 0u};
    *(uint4*)&feat_t[((size_t)y * FT + x) * 512 + part * 8] = z;
}

__global__ void k_zero_border_px(float* __restrict__ feat_px) {
    int t = blockIdx.x * 256 + threadIdx.x;
    int total = 804 * 128;           // 512 f32 = 128 x float4 per px
    if (t >= total) return;
    int px = t >> 7, part = t & 127;
    int y, x;
    if (px < 202)      { y = 0;   x = px; }
    else if (px < 404) { y = 201; x = px - 202; }
    else if (px < 604) { x = 0;   y = 1 + (px - 404); }
    else               { x = 201; y = 1 + (px - 604); }
    float4 z = {0.f, 0.f, 0.f, 0.f};
    *(float4*)&feat_px[((size_t)y * FP + x) * 512 + part * 4] = z;
}

// ---------------------------------------------------------------------------
// FUSED feature transforms: ONE read of feat [512][200][200] produces
//   feat_t  [212][212][512] bf16   and   feat_px [202][202][512] f32
// (was two kernels, each reading the full 160MB feat)
// ---------------------------------------------------------------------------
__global__ void k_feat_both(const float* __restrict__ feat, ushort* __restrict__ feat_t,
                            float* __restrict__ feat_px) {
    __shared__ float lt[32 * 8 * 33];
    int x0 = blockIdx.x * 32, y0 = blockIdx.y * 8, ci0 = blockIdx.z * 32;
    int tid = threadIdx.x;
    for (int u = tid; u < 8192; u += 256) {
        int ciL = u >> 8, rem = u & 255;
        int yy = rem >> 5, xx = rem & 31;
        int x = x0 + xx;
        float v = (x < W_) ? feat[(size_t)(ci0 + ciL) * HW_ + (y0 + yy) * W_ + x] : 0.f;
        lt[(ciL * 8 + yy) * 33 + xx] = v;
    }
    __syncthreads();
    for (int u = tid; u < 1024; u += 256) {
        int pxu = u >> 2, part = u & 3;
        int yy = pxu >> 5, xx = pxu & 31;
        if (x0 + xx >= W_) continue;
        float tmp[8];
        ushort tb[8];
#pragma unroll
        for (int k = 0; k < 8; ++k) {
            tmp[k] = lt[((part * 8 + k) * 8 + yy) * 33 + xx];
            tb[k] = f2bf(tmp[k]);
        }
        float* dst = &feat_px[((size_t)(y0 + yy + 1) * FP + (x0 + xx + 1)) * 512 + ci0 + part * 8];
        *(float4*)&dst[0] = *(const float4*)&tmp[0];
        *(float4*)&dst[4] = *(const float4*)&tmp[4];
        *(uint4*)&feat_t[((size_t)(y0 + yy + 1) * FT + (x0 + xx + 1)) * 512 + ci0 + part * 8] =
            *(const uint4*)&tb[0];
    }
}

// ---------------------------------------------------------------------------
// FUSED weight transforms: one strided read of conv_w produces
//   wt_t  [tap9][co512][ci512] bf16   and   wt_ex [k'][co512] f32
// ---------------------------------------------------------------------------
__global__ void k_wt_both(const float* __restrict__ conv_w, ushort* __restrict__ wt_t,
                          float* __restrict__ wt_ex) {
    __shared__ float t[32][33];
    int kb = blockIdx.x * 32;   // k' base (4608/32 = 144), single tap per tile
    int cb = blockIdx.y * 32;
    int lx = threadIdx.x, ly = threadIdx.y;
    int tap = kb >> 9, ci0 = kb & 511;
    for (int r = ly; r < 32; r += 8) {
        float v = conv_w[((size_t)(cb + r) * 512 + ci0 + lx) * 9 + tap];
        t[r][lx] = v;
        wt_t[(size_t)tap * 262144 + (size_t)(cb + r) * 512 + ci0 + lx] = f2bf(v);
    }
    __syncthreads();
    for (int r = ly; r < 32; r += 8)
        wt_ex[(size_t)(kb + r) * 512 + cb + lx] = t[lx][r];
}

// ---------------------------------------------------------------------------
// Approx conv v6: bf16 MFMA 16x16x32. Block = 64 co x (16x32 px), 4 waves.
// FUSED cls head via MFMA (not shuffles -- R13's mistake): after the K-loop,
// relu(x) is dumped as bf16 into the freed staging LDS as xl[512][72]
// (72-pad: l15-stride-36-word reads -> 2 lanes/bank, free per m136), then
// each wave runs 8 groups x 2 chained 16x16x32 MFMAs against a cls_w B-frag
// (N=16, a<9 valid, rest zero) and writes cls_part[cot][px*9+a].
// xab (41MB) and the separate k_cls pass are DELETED.
// Fragment mapping (m89-verified, same as conv's own): A: M=l15, k=l4*8+j;
// D: M=l4*4+r, N=l15.
// ---------------------------------------------------------------------------
__global__ __launch_bounds__(256)
__attribute__((amdgpu_waves_per_eu(2, 4)))
void k_conv3_mfma(const ushort* __restrict__ feat_t, const ushort* __restrict__ wt_t,
                  const float* __restrict__ bias, const float* __restrict__ cls_w,
                  float* __restrict__ cls_part) {
    __shared__ ushort smem[18 * 34 * 32 + 9 * 64 * 32];   // 76.0 KB
    ushort* halo = smem;                    // [r][c34][32ci] 19584 ushorts
    ushort* wtile = smem + 18 * 34 * 32;    // [tap][co][32ci] 18432 ushorts
    int b = blockIdx.x;
    int cot = b & 7;            // XCD-aligned co-slice (728 = 8 x 91, bijective)
    int tile = b >> 3;          // 0..90
    int xt = tile % 7, yt = tile / 7;
    int x0 = xt * 32, y0 = yt * 16;
    int co0 = cot * 64;
    int tid = threadIdx.x;
    int lane = tid & 63, wid = tid >> 6;
    int l15 = lane & 15, l4 = lane >> 4;

    f32x4 acc[4][2][4];
#pragma unroll
    for (int i = 0; i < 4; ++i)
#pragma unroll
        for (int h = 0; h < 2; ++h)
#pragma unroll
            for (int j = 0; j < 4; ++j) acc[i][h][j] = (f32x4){0.f, 0.f, 0.f, 0.f};

    for (int ch = 0; ch < 16; ++ch) {
        int ci0 = ch * 32;
        __syncthreads();   // previous chunk's LDS reads done
        for (int u = tid; u < 2448; u += 256) {
            int p = u >> 2, q = u & 3;
            int r = p / 34, c = p - r * 34;
            const ushort* src = feat_t + ((size_t)(y0 + r) * FT + (x0 + c)) * 512 + ci0 + q * 8;
            gload_lds16(src, &halo[(u & ~63) * 8]);
        }
        for (int u = tid; u < 2304; u += 256) {
            int row = u >> 2, q = u & 3;       // row = tap*64 + co
            int tap = row >> 6, co = row & 63;
            const ushort* src = wt_t + ((size_t)(tap * 512 + co0 + co)) * 512 + ci0 + q * 8;
            gload_lds16(src, &wtile[(u & ~63) * 8]);
        }
        __syncthreads();   // drains vmcnt -> LDS valid
#pragma unroll
        for (int tap = 0; tap < 9; ++tap) {
            int th = tap / 3, tw = tap - th * 3;
            bf16x8 af[4][2];
#pragma unroll
            for (int pi = 0; pi < 4; ++pi)
#pragma unroll
                for (int xh = 0; xh < 2; ++xh)
                    af[pi][xh] = *(const bf16x8*)&halo[
                        ((wid * 4 + pi + th) * 34 + (xh * 16 + l15 + tw)) * 32 + l4 * 8];
#pragma unroll
            for (int cj = 0; cj < 4; ++cj) {
                bf16x8 bf = *(const bf16x8*)&wtile[(tap * 64 + cj * 16 + l15) * 32 + l4 * 8];
#pragma unroll
                for (int pi = 0; pi < 4; ++pi)
#pragma unroll
                    for (int xh = 0; xh < 2; ++xh)
                        acc[pi][xh][cj] = __builtin_amdgcn_mfma_f32_16x16x32_bf16(
                            af[pi][xh], bf, acc[pi][xh][cj], 0, 0, 0);
            }
        }
    }

    // ---- epilogue: x -> bf16 into xl[512][72] (reuse staging LDS) ----
    __syncthreads();                       // all staging reads done
    ushort* xl = smem;                     // 512*72 = 36864 ushorts <= 38016
    float bv[4];
#pragma unroll
    for (int cj = 0; cj < 4; ++cj) bv[cj] = bias[co0 + cj * 16 + l15];
#pragma unroll
    for (int pi = 0; pi < 4; ++pi) {
#pragma unroll
        for (int xh = 0; xh < 2; ++xh) {
#pragma unroll
            for (int cj = 0; cj < 4; ++cj) {
                int co = cj * 16 + l15;
#pragma unroll
                for (int r = 0; r < 4; ++r) {
                    int px = (wid * 4 + pi) * 32 + xh * 16 + l4 * 4 + r;
                    float v = acc[pi][xh][cj][r] + bv[cj];
                    xl[px * 72 + co] = f2bf(v > 0.f ? v : 0.f);
                }
            }
        }
    }
    __syncthreads();

    // ---- cls via MFMA: P[16px][16a] = X[16px][64co] * Wc[64co][16a] ----
    bf16x8 b0, b1;
#pragma unroll
    for (int j = 0; j < 8; ++j) {
        b0[j] = (l15 < 9) ? (short)f2bf(cls_w[l15 * 512 + co0 + l4 * 8 + j]) : (short)0;
        b1[j] = (l15 < 9) ? (short)f2bf(cls_w[l15 * 512 + co0 + 32 + l4 * 8 + j]) : (short)0;
    }
#pragma unroll
    for (int gg = 0; gg < 8; ++gg) {
        int g = wid * 8 + gg;
        bf16x8 a0 = *(const bf16x8*)&xl[(g * 16 + l15) * 72 + l4 * 8];
        bf16x8 a1 = *(const bf16x8*)&xl[(g * 16 + l15) * 72 + 32 + l4 * 8];
        f32x4 p = (f32x4){0.f, 0.f, 0.f, 0.f};
        p = __builtin_amdgcn_mfma_f32_16x16x32_bf16(a0, b0, p, 0, 0, 0);
        p = __builtin_amdgcn_mfma_f32_16x16x32_bf16(a1, b1, p, 0, 0, 0);
        if (l15 < 9) {
#pragma unroll
            for (int r = 0; r < 4; ++r) {
                int px = g * 16 + l4 * 4 + r;
                int row = px >> 5, col = px & 31;
                int yy = y0 + row, xx = x0 + col;
                if (yy < H_ && xx < W_)
                    cls_part[(size_t)cot * NANCH + ((size_t)yy * W_ + xx) * 9 + l15] = p[r];
            }
        }
    }
}

// ---------------------------------------------------------------------------
// cls finalize: fixed-order sum of 8 co-slice partials + bias -> sigmoid
// ---------------------------------------------------------------------------
__global__ void k_cls_fin(const float* __restrict__ cls_part, const float* __restrict__ cls_b,
                          float* __restrict__ scores) {
    int i = blockIdx.x * 256 + threadIdx.x;
    if (i >= NANCH) return;
    float s = 0.f;
#pragma unroll
    for (int c = 0; c < 8; ++c) s += cls_part[(size_t)c * NANCH + i];
    int a = i % 9;
    scores[i] = 1.f / (1.f + expf(-(s + cls_b[a])));
}

// ---------------------------------------------------------------------------
// Radix-select helpers
// meta: [0]=P [1]=cntAboveP [2]=T [3]=cntGtT [4]=need [8]=atomGt [9]=atomEq [10]=npx
// ---------------------------------------------------------------------------
__global__ void k_hist1_lds(const float* __restrict__ scores, unsigned* __restrict__ hist) {
    __shared__ unsigned h[16384];
    int tid = threadIdx.x;
    for (int j = tid; j < 16384; j += 256) h[j] = 0u;
    __syncthreads();
    int stride = gridDim.x * 256;
    for (int i = blockIdx.x * 256 + tid; i < NANCH; i += stride)
        atomicAdd(&h[(__float_as_uint(scores[i]) >> 16) & 16383], 1u);
    __syncthreads();
    for (int j = tid; j < 16384; j += 256) {
        unsigned v = h[j];
        if (v) atomicAdd(&hist[j], v);
    }
}

__global__ void k_find_thr(const unsigned* __restrict__ hist, unsigned* __restrict__ meta,
                           int mode, int Kwant) {
    __shared__ unsigned csum[1024];
    int t = threadIdx.x;
    unsigned base = (mode == 0) ? 0u : meta[1];
    unsigned s = 0;
    for (int b = 0; b < 64; ++b) s += hist[t * 64 + b];
    csum[t] = s;
    __syncthreads();
    for (int off = 1; off < 1024; off <<= 1) {
        unsigned add = (t + off < 1024) ? csum[t + off] : 0u;
        __syncthreads();
        csum[t] += add;
        __syncthreads();
    }
    unsigned run = base + ((t < 1023) ? csum[t + 1] : 0u);
    for (int b = 63; b >= 0; --b) {
        unsigned h = hist[t * 64 + b];
        if (run < (unsigned)Kwant && run + h >= (unsigned)Kwant) {
            if (mode == 0) {
                meta[0] = (unsigned)(t * 64 + b);
                meta[1] = run;
            } else {
                meta[2] = (meta[0] << 16) | (unsigned)(t * 64 + b);
                meta[3] = run;
                meta[4] = (unsigned)Kwant - run;
            }
            break;
        }
        run += h;
    }
}

// FUSED candidate collection: per-px check of its 9 anchors + compaction.
// flags pre-zeroed upfront; px_list order nondeterministic but the slot->px
// map is used consistently (output invariant).
__global__ void k_cand(const float* __restrict__ scores, unsigned* __restrict__ meta,
                       unsigned* __restrict__ flags, unsigned* __restrict__ px_list) {
    int px = blockIdx.x * 256 + threadIdx.x;
    if (px >= HW_) return;
    unsigned P = meta[0];
    const float* s = &scores[(size_t)px * 9];
    bool any = false;
#pragma unroll
    for (int a = 0; a < 9; ++a) any |= ((__float_as_uint(s[a]) >> 16) >= P);
    if (any) {
        unsigned sl = atomicAdd(&meta[10], 1u);
        if (sl < (unsigned)PXCAP) { px_list[sl] = (unsigned)px; flags[px] = sl + 1u; }
    }
}

// ---------------------------------------------------------------------------
// Exact fp32 conv GEMM: C[64co x 64px], K split x8 (576 each). 64-k LDS
// staging (two 32-halves; 512%32==0 so each half is within one tap).
// Same accumulation order (k ascending) -> deterministic.
// ---------------------------------------------------------------------------
__global__ __attribute__((amdgpu_waves_per_eu(2, 4)))
void k_exact_gemm(const float* __restrict__ feat_px, const float* __restrict__ wt_ex,
                  const unsigned* __restrict__ meta, const unsigned* __restrict__ px_list,
                  float* __restrict__ xpart) {
    int npx = (int)meta[10]; if (npx > PXCAP) npx = PXCAP;
    int pb = blockIdx.x;
    if (pb * 64 >= npx) return;
    int cot = blockIdx.y;           // 0..7 -> 64 co
    int kz = blockIdx.z;            // 0..7 -> K = 576
    __shared__ float A[64][68];
    __shared__ float B[64][68];
    __shared__ int plist[64];
    int tid = threadIdx.x;
    int co0 = cot * 64;
    if (tid < 64) {
        int slot = pb * 64 + tid;
        plist[tid] = (slot < npx) ? (int)px_list[slot] : (int)px_list[0];
    }
    int tcog = tid >> 4;   // 16 groups x 4 co
    int tpxg = tid & 15;   // 16 groups x 4 px
    float acc[4][4];
#pragma unroll
    for (int i = 0; i < 4; ++i)
#pragma unroll
        for (int j = 0; j < 4; ++j) acc[i][j] = 0.f;
    int kbase = kz * 576;
    for (int kc = 0; kc < 9; ++kc) {
        int k0 = kbase + kc * 64;
        __syncthreads();                                 // covers plist on kc==0
        for (int u = tid; u < 1024; u += 256) {          // A: 64k x 64co from wt_ex
            int k = u >> 4, cp = (u & 15) * 4;
            *(float4*)&A[k][cp] = *(const float4*)&wt_ex[(size_t)(k0 + k) * 512 + co0 + cp];
        }
#pragma unroll
        for (int hh = 0; hh < 2; ++hh) {                 // B: two 32-k halves
            int kh = k0 + hh * 32;
            int tap = kh >> 9, ci0c = kh & 511;
            int th = tap / 3, tw = tap - th * 3;
            for (int u = tid; u < 512; u += 256) {
                int s = u >> 3, part = u & 7;
                int px = plist[s];
                int y = px / W_, x = px - y * W_;
                float4 v = *(const float4*)&feat_px[((size_t)(y + th) * FP + (x + tw)) * 512 + ci0c + part * 4];
                B[hh * 32 + part * 4 + 0][s] = v.x; B[hh * 32 + part * 4 + 1][s] = v.y;
                B[hh * 32 + part * 4 + 2][s] = v.z; B[hh * 32 + part * 4 + 3][s] = v.w;
            }
        }
        __syncthreads();
#pragma unroll 4
        for (int k = 0; k < 64; ++k) {
            float wv[4], pv[4];
            *(float4*)&wv[0] = *(const float4*)&A[k][tcog * 4];
            *(float4*)&pv[0] = *(const float4*)&B[k][tpxg * 4];
#pragma unroll
            for (int i = 0; i < 4; ++i)
#pragma unroll
                for (int j = 0; j < 4; ++j) acc[i][j] = fmaf(wv[i], pv[j], acc[i][j]);
        }
    }
#pragma unroll
    for (int j = 0; j < 4; ++j) {
        int slot = pb * 64 + tpxg * 4 + j;
        if (slot >= npx) continue;
        f32x4 tmp;
        tmp[0] = acc[0][j]; tmp[1] = acc[1][j]; tmp[2] = acc[2][j]; tmp[3] = acc[3][j];
        __builtin_nontemporal_store(tmp,
            (f32x4*)&xpart[((size_t)kz * PXCAP + slot) * 512 + co0 + tcog * 4]);
    }
}

// ---------------------------------------------------------------------------
// MERGED exact finalize: fixed-order K-split reduce + bias + relu -> xex,
// then the 9 exact anchor scores.
// ---------------------------------------------------------------------------
__global__ void k_exact_fin(const float* __restrict__ xpart, const float* __restrict__ bias,
                            const float* __restrict__ cls_w, const float* __restrict__ cls_b,
                            const unsigned* __restrict__ meta,
                            float* __restrict__ xex, float* __restrict__ scores_ex) {
    int slot = blockIdx.x;
    int npx = (int)meta[10]; if (npx > PXCAP) npx = PXCAP;
    if (slot >= npx) return;
    int l = threadIdx.x;               // 64
    float xv[8];
#pragma unroll
    for (int j = 0; j < 8; ++j) {
        int co = j * 64 + l;
        float v = 0.f;
#pragma unroll
        for (int kz = 0; kz < KSPLIT; ++kz)
            v += __builtin_nontemporal_load(&xpart[((size_t)kz * PXCAP + slot) * 512 + co]);
        v += bias[co];
        v = v > 0.f ? v : 0.f;
        xex[(size_t)slot * 512 + co] = v;
        xv[j] = v;
    }
#pragma unroll
    for (int a = 0; a < 9; ++a) {
        float s = 0.f;
#pragma unroll
        for (int k = 0; k < 8; ++k) s = fmaf(xv[k], cls_w[a * 512 + k * 64 + l], s);
#pragma unroll
        for (int o = 32; o > 0; o >>= 1) s += __shfl_down(s, o);
        if (l == 0) scores_ex[slot * 9 + a] = 1.f / (1.f + expf(-(s + cls_b[a])));
    }
}

__global__ void k_hist1_ex_lds(const float* __restrict__ scores_ex, const unsigned* __restrict__ meta,
                               unsigned* __restrict__ hist) {
    __shared__ unsigned h[16384];
    int npx = (int)meta[10]; if (npx > PXCAP) npx = PXCAP;
    int n = npx * 9;
    int tid = threadIdx.x;
    for (int j = tid; j < 16384; j += 256) h[j] = 0u;
    __syncthreads();
    for (int i = blockIdx.x * 256 + tid; i < n; i += 32 * 256)
        atomicAdd(&h[(__float_as_uint(scores_ex[i]) >> 16) & 16383], 1u);
    __syncthreads();
    for (int j = tid; j < 16384; j += 256) {
        unsigned v = h[j];
        if (v) atomicAdd(&hist[j], v);
    }
}

__global__ void k_hist2_ex(const float* __restrict__ scores_ex, const unsigned* __restrict__ meta,
                           const unsigned* __restrict__ meta_ex, unsigned* __restrict__ hist2) {
    int npx = (int)meta[10]; if (npx > PXCAP) npx = PXCAP;
    int i = blockIdx.x * 256 + threadIdx.x;
    if (i >= npx * 9) return;
    unsigned b = __float_as_uint(scores_ex[i]);
    if ((b >> 16) == meta_ex[0]) atomicAdd(&hist2[b & 0xFFFFu], 1u);
}

__global__ void k_collect_ex(const float* __restrict__ scores_ex, const unsigned* __restrict__ meta,
                             unsigned* __restrict__ meta_ex, const unsigned* __restrict__ px_list,
                             unsigned* __restrict__ sel_bits, unsigned* __restrict__ sel_idx,
                             unsigned* __restrict__ eq_idx) {
    int npx = (int)meta[10]; if (npx > PXCAP) npx = PXCAP;
    int i = blockIdx.x * 256 + threadIdx.x;
    if (i >= npx * 9) return;
    unsigned b = __float_as_uint(scores_ex[i]);
    unsigned T = meta_ex[2];
    unsigned g = px_list[i / 9] * 9u + (unsigned)(i % 9);
    if (b > T) {
        unsigned s = atomicAdd(&meta_ex[8], 1u);
        if (s < 1024u) { sel_bits[s] = b; sel_idx[s] = g; }
    } else if (b == T) {
        unsigned s = atomicAdd(&meta_ex[9], 1u);
        if (s < 65536u) eq_idx[s] = g;
    }
}

// exact stable top-1000 (ties -> smallest global idx), bitonic final order
__global__ void k_topk_final(const unsigned* __restrict__ sel_bits, const unsigned* __restrict__ sel_idx,
                             const unsigned* __restrict__ eq_idx, const unsigned* __restrict__ meta,
                             unsigned* __restrict__ top_idx, float* __restrict__ top_sc) {
    __shared__ uint64_t keys[1024];
    __shared__ int lcnt;
    __shared__ int lred;
    int t = threadIdx.x;
    unsigned cntGt = meta[3];
    unsigned need = meta[4];
    unsigned cntEq = meta[9];
    unsigned T = meta[2];

    unsigned idx_cut = 0xFFFFFFFFu;
    if (cntEq > need) {
        unsigned lo = 0, hi = NANCH - 1;
        while (lo < hi) {
            unsigned mid = (lo + hi) >> 1;
            int c = 0;
            for (unsigned e = t; e < cntEq; e += 1024)
                if (eq_idx[e] <= mid) c++;
            if (t == 0) lred = 0;
            __syncthreads();
            atomicAdd(&lred, c);
            __syncthreads();
            int tot = lred;
            __syncthreads();
            if ((unsigned)tot >= need) hi = mid; else lo = mid + 1;
        }
        idx_cut = lo;
    }

    keys[t] = 0ull;
    if (t == 0) lcnt = 0;
    __syncthreads();
    for (unsigned s = t; s < cntGt; s += 1024)
        keys[s] = ((uint64_t)sel_bits[s] << 32) | (uint64_t)(0xFFFFFFFFu - sel_idx[s]);
    for (unsigned e = t; e < cntEq; e += 1024) {
        unsigned ix = eq_idx[e];
        if (ix <= idx_cut) {
            int s2 = (int)cntGt + atomicAdd(&lcnt, 1);
            keys[s2] = ((uint64_t)T << 32) | (uint64_t)(0xFFFFFFFFu - ix);
        }
    }
    __syncthreads();
    for (int k = 2; k <= 1024; k <<= 1) {
        for (int j = k >> 1; j > 0; j >>= 1) {
            int ixj = t ^ j;
            if (ixj > t) {
                uint64_t a = keys[t], b = keys[ixj];
                bool desc = (t & k) == 0;
                if (desc ? (a < b) : (a > b)) { keys[t] = b; keys[ixj] = a; }
            }
            __syncthreads();
        }
    }
    if (t < KPRE) {
        top_sc[t] = __uint_as_float((unsigned)(keys[t] >> 32));
        top_idx[t] = 0xFFFFFFFFu - (unsigned)keys[t];
    }
}

// ---------------------------------------------------------------------------
// decode from exact x (via flags px->slot map)
// ---------------------------------------------------------------------------
__global__ void k_decode(const float* __restrict__ xex, const unsigned* __restrict__ flags,
                         const float* __restrict__ reg_w, const float* __restrict__ reg_b,
                         const unsigned* __restrict__ top_idx,
                         float* __restrict__ props, float* __restrict__ areas) {
    int j = blockIdx.x;
    int lane = threadIdx.x;  // 64
    unsigned idx = top_idx[j];
    int pix = (int)(idx / 9u);
    int a = (int)(idx - (unsigned)pix * 9u);
    int slot = (int)flags[pix] - 1;
    if (slot < 0) slot = 0;
    const float* xr = xex + (size_t)slot * 512;
    float s0 = 0, s1 = 0, s2 = 0, s3 = 0;
    for (int c = lane; c < C_; c += 64) {
        float xv = xr[c];
        s0 = fmaf(xv, reg_w[(a * 4 + 0) * C_ + c], s0);
        s1 = fmaf(xv, reg_w[(a * 4 + 1) * C_ + c], s1);
        s2 = fmaf(xv, reg_w[(a * 4 + 2) * C_ + c], s2);
        s3 = fmaf(xv, reg_w[(a * 4 + 3) * C_ + c], s3);
    }
#pragma unroll
    for (int o = 32; o > 0; o >>= 1) {
        s0 += __shfl_down(s0, o);
        s1 += __shfl_down(s1, o);
        s2 += __shfl_down(s2, o);
        s3 += __shfl_down(s3, o);
    }
    if (lane == 0) {
        float d0 = s0 + reg_b[a * 4 + 0];
        float d1 = s1 + reg_b[a * 4 + 1];
        float d2 = s2 + reg_b[a * 4 + 2];
        float d3 = s3 + reg_b[a * 4 + 3];
        int h = pix / W_, w2 = pix - h * W_;
        int rr = a / 3, ss = a - rr * 3;
        float ratio = (rr == 0) ? 0.5f : (rr == 1) ? 1.0f : 2.0f;
        float scale = (ss == 0) ? 128.f : (ss == 1) ? 256.f : 512.f;
        float hr = sqrtf(ratio);
        float wr = 1.0f / hr;
        float wsc = wr * scale, hsc = hr * scale;
        float sx = (float)w2 * 16.f, sy = (float)h * 16.f;
        float a0 = sx - wsc * 0.5f, a1 = sy - hsc * 0.5f;
        float a2 = sx + wsc * 0.5f, a3 = sy + hsc * 0.5f;
        float bw = a2 - a0, bh = a3 - a1;
        float cx = a0 + 0.5f * bw, cy = a1 + 0.5f * bh;
        float px = d0 * bw + cx, py = d1 * bh + cy;
        float pw = expf(d2) * bw, ph = expf(d3) * bh;
        float b0 = px - 0.5f * pw, b1 = py - 0.5f * ph;
        float b2 = px + 0.5f * pw, b3 = py + 0.5f * ph;
        b0 = fminf(fmaxf(b0, 0.f), 3200.f);
        b1 = fminf(fmaxf(b1, 0.f), 3200.f);
        b2 = fminf(fmaxf(b2, 0.f), 3200.f);
        b3 = fminf(fmaxf(b3, 0.f), 3200.f);
        props[j * 4 + 0] = b0;
        props[j * 4 + 1] = b1;
        props[j * 4 + 2] = b2;
        props[j * 4 + 3] = b3;
        areas[j] = (b2 - b0) * (b3 - b1);
    }
}

// ---------------------------------------------------------------------------
__global__ void k_nms_mask(const float* __restrict__ props, const float* __restrict__ areas,
                           unsigned long long* __restrict__ mask, float* __restrict__ out) {
    int i = blockIdx.x;
    int tid = threadIdx.x;  // 256
    if (i == 0) {
        for (int t = tid; t < KPOST * 5; t += 256) out[t] = 0.f;
    }
    float x1i = props[i * 4 + 0], y1i = props[i * 4 + 1];
    float x2i = props[i * 4 + 2], y2i = props[i * 4 + 3];
    float ai = areas[i];
#pragma unroll
    for (int k = 0; k < 4; ++k) {
        int j = k * 256 + tid;
        bool sup = false;
        if (j < KPRE && j > i) {
            float iw = fminf(x2i, props[j * 4 + 2]) - fmaxf(x1i, props[j * 4 + 0]);
            float ih = fminf(y2i, props[j * 4 + 3]) - fmaxf(y1i, props[j * 4 + 1]);
            iw = fmaxf(iw, 0.f);
            ih = fmaxf(ih, 0.f);
            float inter = iw * ih;
            float iou = inter / (ai + areas[j] - inter);
            sup = iou > 0.7f;
        }
        unsigned long long b = __ballot(sup);
        int word = k * 4 + (tid >> 6);
        if ((tid & 63) == 0) mask[(size_t)i * 16 + word] = b;
    }
}

// ---------------------------------------------------------------------------
// NMS scan: kept-box iteration with early exit at 100 kept.
// ---------------------------------------------------------------------------
__global__ void k_nms_scan_out(const unsigned long long* __restrict__ mask,
                               const float* __restrict__ props, const float* __restrict__ top_sc,
                               float* __restrict__ out) {
    __shared__ int kidx[KPOST];
    __shared__ int nk;
    int lane = threadIdx.x;  // 64
    if (lane == 0) {
        unsigned long long k0 = ~0ull, k1 = ~0ull, k2 = ~0ull, k3 = ~0ull;
        unsigned long long k4 = ~0ull, k5 = ~0ull, k6 = ~0ull, k7 = ~0ull;
        unsigned long long k8 = ~0ull, k9 = ~0ull, k10 = ~0ull, k11 = ~0ull;
        unsigned long long k12 = ~0ull, k13 = ~0ull, k14 = ~0ull;
        unsigned long long k15 = (1ull << 40) - 1ull;   // 1000 bits total
        int kept = 0;
#define APPLY_ROW(ii) { const unsigned long long* row = &mask[(size_t)(ii) * 16];          \
        k0 &= ~row[0];  k1 &= ~row[1];  k2 &= ~row[2];  k3 &= ~row[3];                     \
        k4 &= ~row[4];  k5 &= ~row[5];  k6 &= ~row[6];  k7 &= ~row[7];                     \
        k8 &= ~row[8];  k9 &= ~row[9];  k10 &= ~row[10]; k11 &= ~row[11];                  \
        k12 &= ~row[12]; k13 &= ~row[13]; k14 &= ~row[14]; k15 &= ~row[15]; }
#define SCAN_WORD(w, kw) { \
        unsigned long long rem = kw; \
        while (rem) { \
            int b = __builtin_ctzll(rem); \
            kidx[kept++] = (w) * 64 + b; \
            if (kept == KPOST) goto done; \
            APPLY_ROW((w) * 64 + b); \
            rem &= kw; \
            rem &= (b >= 63) ? 0ull : ~((2ull << b) - 1ull); \
        } }
        SCAN_WORD(0, k0)  SCAN_WORD(1, k1)  SCAN_WORD(2, k2)  SCAN_WORD(3, k3)
        SCAN_WORD(4, k4)  SCAN_WORD(5, k5)  SCAN_WORD(6, k6)  SCAN_WORD(7, k7)
        SCAN_WORD(8, k8)  SCAN_WORD(9, k9)  SCAN_WORD(10, k10) SCAN_WORD(11, k11)
        SCAN_WORD(12, k12) SCAN_WORD(13, k13) SCAN_WORD(14, k14) SCAN_WORD(15, k15)
done:
        nk = kept;
#undef SCAN_WORD
#undef APPLY_ROW
    }
    __syncthreads();
    int n = nk;
    for (int t = lane; t < KPOST; t += 64) {
        if (t < n) {
            int i = kidx[t];
            out[t * 4 + 0] = props[i * 4 + 0];
            out[t * 4 + 1] = props[i * 4 + 1];
            out[t * 4 + 2] = props[i * 4 + 2];
            out[t * 4 + 3] = props[i * 4 + 3];
            out[KPOST * 4 + t] = top_sc[i];
        }
    }
}

// ---------------------------------------------------------------------------
extern "C" void kernel_launch(void* const* d_in, const int* in_sizes, int n_in,
                              void* d_out, int out_size, void* d_ws, size_t ws_size,
                              hipStream_t stream) {
    const float* feat   = (const float*)d_in[0];
    const float* conv_w = (const float*)d_in[1];
    const float* conv_b = (const float*)d_in[2];
    const float* cls_w  = (const float*)d_in[3];
    const float* cls_b  = (const float*)d_in[4];
    const float* reg_w  = (const float*)d_in[5];
    const float* reg_b  = (const float*)d_in[6];
    float* out = (float*)d_out;

    size_t off = 0;
    auto alloc = [&](size_t bytes) -> void* {
        off = (off + 255) & ~(size_t)255;
        void* p = (char*)d_ws + off;
        off += bytes;
        return p;
    };
    ushort* feat_t  = (ushort*)alloc((size_t)FT * FT * 512 * 2);        // 46.0 MB
    float*  feat_px = (float*)alloc((size_t)FP * FP * 512 * 4);         // 83.6 MB
    ushort* wt_t    = (ushort*)alloc((size_t)9 * 512 * 512 * 2);        // 4.7 MB
    float*  wt_ex   = (float*)alloc((size_t)9 * 512 * 512 * 4);         // 9.4 MB
    float*  cls_part = (float*)alloc((size_t)8 * NANCH * 4);            // 11.5 MB
    float*  xpart   = (float*)alloc((size_t)KSPLIT * PXCAP * 512 * 4);  // 67 MB
    float*  xex     = (float*)alloc((size_t)PXCAP * 512 * 4);           // 8.4 MB
    float*  scores  = (float*)alloc((size_t)NANCH * 4);                 // 1.44 MB
    float*  scores_ex = (float*)alloc((size_t)PXCAP * 9 * 4);
    // contiguous zero region: hist1, hist2, hist1e, hist2e, meta, meta_ex, flags
    unsigned* hist1   = (unsigned*)alloc(65536 * 4);
    unsigned* hist2   = (unsigned*)alloc(65536 * 4);
    unsigned* hist1e  = (unsigned*)alloc(65536 * 4);
    unsigned* hist2e  = (unsigned*)alloc(65536 * 4);
    unsigned* meta    = (unsigned*)alloc(64 * 4);
    unsigned* meta_ex = (unsigned*)alloc(64 * 4);
    unsigned* flags   = (unsigned*)alloc((size_t)HW_ * 4);
    unsigned* px_list = (unsigned*)alloc(PXCAP * 4);
    unsigned* sel_bits = (unsigned*)alloc(1024 * 4);
    unsigned* sel_idx  = (unsigned*)alloc(1024 * 4);
    unsigned* eq_idx   = (unsigned*)alloc(65536 * 4);
    unsigned* top_idx  = (unsigned*)alloc(KPRE * 4);
    float* top_sc      = (float*)alloc(KPRE * 4);
    float* props       = (float*)alloc(KPRE * 4 * 4);
    float* areas       = (float*)alloc(KPRE * 4);
    unsigned long long* mask = (unsigned long long*)alloc((size_t)KPRE * 16 * 8);
    (void)ws_size; (void)in_sizes; (void)n_in; (void)out_size;

    // 0) prep: borders + single upfront zero of all hist/meta/flags;
    //    single-read fused feature + weight transforms
    k_zero_border_t<<<(4944 * 64 + 255) / 256, 256, 0, stream>>>(feat_t);
    k_zero_border_px<<<(804 * 128 + 255) / 256, 256, 0, stream>>>(feat_px);
    int zrDw = 65536 * 4 + 128 + HW_;
    k_zero_u32<<<(zrDw + 255) / 256, 256, 0, stream>>>(hist1, zrDw);
    k_feat_both<<<dim3(7, 25, 16), 256, 0, stream>>>(feat, feat_t, feat_px);
    k_wt_both<<<dim3(144, 16), dim3(32, 8), 0, stream>>>(conv_w, wt_t, wt_ex);
    // 1) approx conv with FUSED MFMA cls partials -> finalize scores
    k_conv3_mfma<<<8 * 91, 256, 0, stream>>>(feat_t, wt_t, conv_b, cls_w, cls_part);
    k_cls_fin<<<(NANCH + 255) / 256, 256, 0, stream>>>(cls_part, cls_b, scores);
    // 2) candidate pixels: approx top-KSEL bucket threshold + fused compaction
    k_hist1_lds<<<64, 256, 0, stream>>>(scores, hist1);
    k_find_thr<<<1, 1024, 0, stream>>>(hist1, meta, 0, KSEL);
    k_cand<<<(HW_ + 255) / 256, 256, 0, stream>>>(scores, meta, flags, px_list);
    // 3) exact fp32 conv at candidates: K-split GEMM -> merged finalize
    k_exact_gemm<<<dim3(PXCAP / 64, 8, KSPLIT), 256, 0, stream>>>(feat_px, wt_ex, meta, px_list, xpart);
    k_exact_fin<<<PXCAP, 64, 0, stream>>>(xpart, conv_b, cls_w, cls_b, meta, xex, scores_ex);
    // 4) exact stable top-1000 among candidate anchors (global indices)
    k_hist1_ex_lds<<<32, 256, 0, stream>>>(scores_ex, meta, hist1e);
    k_find_thr<<<1, 1024, 0, stream>>>(hist1e, meta_ex, 0, KPRE);
    k_hist2_ex<<<(PXCAP * 9 + 255) / 256, 256, 0, stream>>>(scores_ex, meta, meta_ex, hist2e);
    k_find_thr<<<1, 1024, 0, stream>>>(hist2e, meta_ex, 1, KPRE);
    k_collect_ex<<<(PXCAP * 9 + 255) / 256, 256, 0, stream>>>(scores_ex, meta, meta_ex, px_list,
                                                              sel_bits, sel_idx, eq_idx);
    k_topk_final<<<1, 1024, 0, stream>>>(sel_bits, sel_idx, eq_idx, meta_ex, top_idx, top_sc);
    // 5) exact decode + NMS
    k_decode<<<KPRE, 64, 0, stream>>>(xex, flags, reg_w, reg_b, top_idx, props, areas);
    k_nms_mask<<<KPRE, 256, 0, stream>>>(props, areas, mask, out);
    k_nms_scan_out<<<1, 64, 0, stream>>>(mask, props, top_sc, out);
}